// Round 8
// baseline (256.958 us; speedup 1.0000x reference)
//
#include <hip/hip_runtime.h>
#include <math.h>

#define EPSBN 1e-5f

constexpr int CIN  = 128;
constexpr int MID  = 64;
constexpr int COUT = 256;
constexpr int KNB  = 32;
constexpr int PKP  = 15;

constexpr int PSTR = 72;           // wfs p-slot stride (elements); 16B-aligned
constexpr int WROW = PKP * PSTR;   // 1080 elements per point-row
constexpr int YROW = 72;           // y row stride (elements)

typedef __bf16 v8bf  __attribute__((ext_vector_type(8)));
typedef float  f32x4 __attribute__((ext_vector_type(4)));

__device__ __forceinline__ float lrelu(float x) { return x >= 0.0f ? x : 0.1f * x; }

// ---- bf16 split helpers (native cvt; RNE; residual-compensated) ----
__device__ __forceinline__ void split1(float v, unsigned short& h, unsigned short& l) {
    __bf16 hb = (__bf16)v;
    float r = v - (float)hb;
    __bf16 lb = (__bf16)r;
    h = __builtin_bit_cast(unsigned short, hb);
    l = __builtin_bit_cast(unsigned short, lb);
}

__device__ __forceinline__ void split_frag8(const float* s, v8bf& hi, v8bf& lo) {
    #pragma unroll
    for (int j = 0; j < 8; ++j) {
        __bf16 hb = (__bf16)s[j];
        float r = s[j] - (float)hb;
        hi[j] = hb;
        lo[j] = (__bf16)r;
    }
}

__device__ __forceinline__ v8bf as_v8bf(uint4 u) {
    union { uint4 u; v8bf v; } X;
    X.u = u;
    return X.v;
}

// bit-trick split (used by prep only; proven)
__device__ __forceinline__ unsigned bf16_rne(float f) {
    unsigned u = __float_as_uint(f);
    return (u + 0x7fffu + ((u >> 16) & 1u)) >> 16;
}
__device__ __forceinline__ void split_pack8(const float* s, v8bf& hi, v8bf& lo) {
    unsigned h[8], l[8];
    #pragma unroll
    for (int j = 0; j < 8; ++j) {
        float a = s[j];
        unsigned hu = bf16_rne(a);
        float r = a - __uint_as_float(hu << 16);
        h[j] = hu;
        l[j] = bf16_rne(r);
    }
    union { uint4 u; v8bf v; } H, L;
    H.u = make_uint4(h[0] | (h[1] << 16), h[2] | (h[3] << 16),
                     h[4] | (h[5] << 16), h[6] | (h[7] << 16));
    L.u = make_uint4(l[0] | (l[1] << 16), l[2] | (l[3] << 16),
                     l[4] | (l[5] << 16), l[6] | (l[7] << 16));
    hi = H.v;
    lo = L.v;
}

// ---------------------------------------------------------------------------
// prep: pack weights into MFMA B-fragment order (hi/lo bf16), precompute BN.
// B-frag: lane l holds B[k = kt*32+(l>>4)*8+j][col = nt*16+(l&15)], one uint4.
//   Wkp: 30kt x 4nt -> 7680 uint4 each (b 0..29)
//   W1:  4kt x 4nt  -> 1024 (b 30..33)
//   Ws:  4kt x 16nt -> 4096 (b 34..49)
//   W2:  2kt x 16nt -> 2048 (b 50..57)
//   bnscale/bnshift[576] (b 58..60): 0..63 bn1, 64..319 bns, 320..575 bn2
// ---------------------------------------------------------------------------
__global__ __launch_bounds__(256) void prep(
    const float* __restrict__ Wkp, const float* __restrict__ W1,
    const float* __restrict__ Ws,  const float* __restrict__ W2,
    const float* __restrict__ g1, const float* __restrict__ b1,
    const float* __restrict__ m1, const float* __restrict__ v1,
    const float* __restrict__ gs, const float* __restrict__ bs,
    const float* __restrict__ ms, const float* __restrict__ vs,
    const float* __restrict__ g2, const float* __restrict__ b2,
    const float* __restrict__ m2, const float* __restrict__ v2,
    uint4* __restrict__ WkpPh, uint4* __restrict__ WkpPl,
    uint4* __restrict__ W1Ph,  uint4* __restrict__ W1Pl,
    uint4* __restrict__ WsPh,  uint4* __restrict__ WsPl,
    uint4* __restrict__ W2Ph,  uint4* __restrict__ W2Pl,
    float* __restrict__ bnscale, float* __restrict__ bnshift)
{
    const int b = blockIdx.x, t = threadIdx.x;
    if (b < 30) {                       // Wkp pack
        int gt = b * 256 + t;
        int lane = gt & 63, rest = gt >> 6;
        int nt = rest & 3, kt = rest >> 2;
        int col = nt * 16 + (lane & 15);
        int kbase = kt * 32 + ((lane >> 4) << 3);
        float tmp[8];
        #pragma unroll
        for (int j = 0; j < 8; ++j)
            tmp[j] = Wkp[(size_t)(kbase + j) * MID + col];
        v8bf hi, lo;
        split_pack8(tmp, hi, lo);
        union { v8bf v; uint4 u; } H, L; H.v = hi; L.v = lo;
        WkpPh[gt] = H.u; WkpPl[gt] = L.u;
    } else if (b < 34) {                // W1 pack (K=128, N=64)
        int gt = (b - 30) * 256 + t;    // [0,1024)
        int lane = gt & 63, rest = gt >> 6;   // [0,16)
        int kt = rest >> 2, nt = rest & 3;
        int col = nt * 16 + (lane & 15);
        int kbase = kt * 32 + ((lane >> 4) << 3);
        float tmp[8];
        #pragma unroll
        for (int j = 0; j < 8; ++j)
            tmp[j] = W1[(size_t)(kbase + j) * MID + col];
        v8bf hi, lo;
        split_pack8(tmp, hi, lo);
        union { v8bf v; uint4 u; } H, L; H.v = hi; L.v = lo;
        W1Ph[gt] = H.u; W1Pl[gt] = L.u;
    } else if (b < 50) {                // Ws pack (K=128, N=256)
        int gt = (b - 34) * 256 + t;    // [0,4096)
        int lane = gt & 63, rest = gt >> 6;   // [0,64)
        int kt = rest >> 4, nt = rest & 15;
        int col = nt * 16 + (lane & 15);
        int kbase = kt * 32 + ((lane >> 4) << 3);
        float tmp[8];
        #pragma unroll
        for (int j = 0; j < 8; ++j)
            tmp[j] = Ws[(size_t)(kbase + j) * COUT + col];
        v8bf hi, lo;
        split_pack8(tmp, hi, lo);
        union { v8bf v; uint4 u; } H, L; H.v = hi; L.v = lo;
        WsPh[gt] = H.u; WsPl[gt] = L.u;
    } else if (b < 58) {                // W2 pack (K=64, N=256)
        int gt = (b - 50) * 256 + t;    // [0,2048)
        int lane = gt & 63, rest = gt >> 6;   // [0,32)
        int kt = rest >> 4, nt = rest & 15;
        int col = nt * 16 + (lane & 15);
        int kbase = kt * 32 + ((lane >> 4) << 3);
        float tmp[8];
        #pragma unroll
        for (int j = 0; j < 8; ++j)
            tmp[j] = W2[(size_t)(kbase + j) * COUT + col];
        v8bf hi, lo;
        split_pack8(tmp, hi, lo);
        union { v8bf v; uint4 u; } H, L; H.v = hi; L.v = lo;
        W2Ph[gt] = H.u; W2Pl[gt] = L.u;
    } else {                            // BN constants, 576 values
        int v = (b - 58) * 256 + t;
        if (v < 576) {
            float g, bb, mm, vv;
            if (v < 64)       { g = g1[v]; bb = b1[v]; mm = m1[v]; vv = v1[v]; }
            else if (v < 320) { int c = v - 64;  g = gs[c]; bb = bs[c]; mm = ms[c]; vv = vs[c]; }
            else              { int c = v - 320; g = g2[c]; bb = b2[c]; mm = m2[c]; vv = v2[c]; }
            float s = g / sqrtf(vv + EPSBN);
            bnscale[v] = s;
            bnshift[v] = bb - mm * s;
        }
    }
}

// ---------------------------------------------------------------------------
// K1 (MFMA, no LDS): x = lrelu(bn1(F @ W1)) -> xp, CHANNEL-PERMUTED packed:
//   xp[n*64 + colr*4 + nt] = (bf16hi<<16 | bf16lo) of x[n][nt*16 + colr]
// so k234's gather is one dwordx4 per lane. A-frags direct from F.
// ---------------------------------------------------------------------------
__global__ __launch_bounds__(256) void k1_mfma(
    const float* __restrict__ F,
    const uint4* __restrict__ W1Ph, const uint4* __restrict__ W1Pl,
    const float* __restrict__ bnscale, const float* __restrict__ bnshift,
    unsigned* __restrict__ xp)
{
    const int t = threadIdx.x;
    const int l = t & 63, w = t >> 6;
    const int n0 = blockIdx.x * 64;
    const int colr = l & 15, kg = l >> 4;
    const int arow = n0 + w * 16 + colr;
    const int k8 = kg * 8;

    const float* fr = F + (size_t)arow * CIN + k8;
    float4 av[4][2];
    #pragma unroll
    for (int kt = 0; kt < 4; ++kt) {
        av[kt][0] = *(const float4*)(fr + kt * 32);
        av[kt][1] = *(const float4*)(fr + kt * 32 + 4);
    }

    f32x4 acc[4];
    #pragma unroll
    for (int nt = 0; nt < 4; ++nt) acc[nt] = (f32x4){0.f, 0.f, 0.f, 0.f};

    #pragma unroll
    for (int kt = 0; kt < 4; ++kt) {
        float tmp[8] = {av[kt][0].x, av[kt][0].y, av[kt][0].z, av[kt][0].w,
                        av[kt][1].x, av[kt][1].y, av[kt][1].z, av[kt][1].w};
        v8bf ah, al;
        split_frag8(tmp, ah, al);
        #pragma unroll
        for (int nt = 0; nt < 4; ++nt) {
            int bidx = (((kt << 2) + nt) << 6) + l;
            v8bf bh = as_v8bf(W1Ph[bidx]);
            v8bf bl = as_v8bf(W1Pl[bidx]);
            acc[nt] = __builtin_amdgcn_mfma_f32_16x16x32_bf16(ah, bh, acc[nt], 0, 0, 0);
            acc[nt] = __builtin_amdgcn_mfma_f32_16x16x32_bf16(al, bh, acc[nt], 0, 0, 0);
            acc[nt] = __builtin_amdgcn_mfma_f32_16x16x32_bf16(ah, bl, acc[nt], 0, 0, 0);
        }
    }

    #pragma unroll
    for (int nt = 0; nt < 4; ++nt) {
        int col = nt * 16 + colr;
        float sc = bnscale[col], sh = bnshift[col];
        #pragma unroll
        for (int r = 0; r < 4; ++r) {
            int row = n0 + w * 16 + kg * 4 + r;
            float val = lrelu(acc[nt][r] * sc + sh);
            unsigned short hu, lu;
            split1(val, hu, lu);
            xp[(size_t)row * MID + colr * 4 + nt] = ((unsigned)hu << 16) | lu;
        }
    }
}

// ---------------------------------------------------------------------------
// K234 (fused KPConv + y-GEMM + tail-GEMM + IN-BLOCK SHORTCUT): 512 thr,
// 16 points/block. Shortcut F@Ws A-loads issued at kernel start (latency
// hidden under phases 1-2); scbuf eliminated.
// Phase 1: per-point wf = h^T @ f via bf16x3 MFMA; gather = 1 dwordx4/lane
//   (channel-permuted xp); hi/lo repack via v_perm_b32.
// Phase 2: y = wf @ Wkp (K=960), split-K across wave pairs.
// Phase 3: out = lrelu( lrelu(bn2(y@W2)) + lrelu(bns(F@Ws)) ).
// ---------------------------------------------------------------------------
__global__ __launch_bounds__(512) void k234_fused(
    const unsigned* __restrict__ xp,
    const float* __restrict__ pts,
    const int* __restrict__ nidx,
    const float* __restrict__ kpp,
    const float* __restrict__ F,
    const uint4* __restrict__ WkpPh, const uint4* __restrict__ WkpPl,
    const uint4* __restrict__ W2Ph,  const uint4* __restrict__ W2Pl,
    const uint4* __restrict__ WsPh,  const uint4* __restrict__ WsPl,
    const float* __restrict__ bnscale, const float* __restrict__ bnshift,
    float* __restrict__ out)
{
    __shared__ unsigned short wfsH[16 * WROW];   // 33.75 KB
    __shared__ unsigned short wfsL[16 * WROW];   // 33.75 KB
    __shared__ float         yP[4][16][17];      // 4.25 KB split-K partials
    __shared__ unsigned short yH[16 * YROW];     // 2.25 KB
    __shared__ unsigned short yL[16 * YROW];     // 2.25 KB

    const int t = threadIdx.x;
    const int l = t & 63, w = t >> 6;            // w in 0..7
    const int col = l & 15, kg = l >> 4;
    const int k8 = kg * 8;
    const int n0 = blockIdx.x * 16;

    // ---- issue shortcut A-loads NOW (consumed in phase 3) ----
    const float* frS = F + (size_t)(n0 + col) * CIN + k8;
    float4 fS[4][2];
    #pragma unroll
    for (int kt = 0; kt < 4; ++kt) {
        fS[kt][0] = *(const float4*)(frS + kt * 32);
        fS[kt][1] = *(const float4*)(frS + kt * 32 + 4);
    }

    // kernel point for this lane's A-row (p = col); p==15 -> h = 0
    float kx = 0.f, ky = 0.f, kz = 0.f;
    if (col < PKP) { kx = kpp[col * 3]; ky = kpp[col * 3 + 1]; kz = kpp[col * 3 + 2]; }

    // ---- phase 1: per-point KPConv via MFMA (2 points per wave) ----
    #pragma unroll
    for (int pt = 0; pt < 2; ++pt) {
        const int pl = w * 2 + pt;
        const int n  = n0 + pl;
        const float cx = pts[(size_t)n * 3];
        const float cy = pts[(size_t)n * 3 + 1];
        const float cz = pts[(size_t)n * 3 + 2];
        const int4 nba = ((const int4*)nidx)[(size_t)n * 8 + kg * 2];
        const int4 nbb = ((const int4*)nidx)[(size_t)n * 8 + kg * 2 + 1];
        int nb[8] = {nba.x, nba.y, nba.z, nba.w, nbb.x, nbb.y, nbb.z, nbb.w};

        // gather packed features: ONE dwordx4 per neighbor (permuted xp);
        // component nt = channel nt*16+col
        unsigned u[8][4];
        #pragma unroll
        for (int j = 0; j < 8; ++j) {
            uint4 X = ((const uint4*)(xp + (size_t)nb[j] * MID))[col];
            u[j][0] = X.x; u[j][1] = X.y; u[j][2] = X.z; u[j][3] = X.w;
        }

        // influence h for (p=col, k=k8+j) -> A-fragment
        float hv[8];
        #pragma unroll
        for (int j = 0; j < 8; ++j) {
            float ex = (pts[(size_t)nb[j] * 3]     - cx) - kx;
            float ey = (pts[(size_t)nb[j] * 3 + 1] - cy) - ky;
            float ez = (pts[(size_t)nb[j] * 3 + 2] - cz) - kz;
            float dist = sqrtf(ex * ex + ey * ey + ez * ez);
            float h = fmaxf(0.0f, 1.0f - dist * 20.0f);   // 1/KP_EXTENT
            hv[j] = (col < PKP) ? h : 0.0f;
        }
        v8bf ah, al;
        split_frag8(hv, ah, al);

        #pragma unroll
        for (int nt = 0; nt < 4; ++nt) {
            unsigned bhW[4], blW[4];
            #pragma unroll
            for (int i = 0; i < 4; ++i) {
                unsigned u0 = u[2 * i][nt], u1 = u[2 * i + 1][nt];
                bhW[i] = __builtin_amdgcn_perm(u1, u0, 0x07060302u);  // {hi16(u1),hi16(u0)}
                blW[i] = __builtin_amdgcn_perm(u1, u0, 0x05040100u);  // {lo16(u1),lo16(u0)}
            }
            v8bf bh = as_v8bf(make_uint4(bhW[0], bhW[1], bhW[2], bhW[3]));
            v8bf bl = as_v8bf(make_uint4(blW[0], blW[1], blW[2], blW[3]));
            f32x4 acc = {0.f, 0.f, 0.f, 0.f};
            acc = __builtin_amdgcn_mfma_f32_16x16x32_bf16(ah, bh, acc, 0, 0, 0);
            acc = __builtin_amdgcn_mfma_f32_16x16x32_bf16(al, bh, acc, 0, 0, 0);
            acc = __builtin_amdgcn_mfma_f32_16x16x32_bf16(ah, bl, acc, 0, 0, 0);
            // D: row p = kg*4+r, col c = nt*16+col; store pre-split bf16
            #pragma unroll
            for (int r = 0; r < 4; ++r) {
                int p = kg * 4 + r;
                if (p < PKP) {
                    unsigned short hu, lu;
                    split1(acc[r], hu, lu);
                    int off = pl * WROW + p * PSTR + nt * 16 + col;
                    wfsH[off] = hu;
                    wfsL[off] = lu;
                }
            }
        }
    }
    __syncthreads();

    // ---- phase 2: y = wf @ Wkp (K=960) split-K across wave pairs ----
    const int nt = w & 3;        // n-tile
    const int khalf = w >> 2;    // 0: kt 0..14, 1: kt 15..29
    f32x4 a0 = {0.f, 0.f, 0.f, 0.f};
    f32x4 a1 = {0.f, 0.f, 0.f, 0.f};
    f32x4 a2 = {0.f, 0.f, 0.f, 0.f};
    #pragma unroll
    for (int i = 0; i < 15; ++i) {
        int kt = khalf * 15 + i;
        int koff = col * WROW + (kt >> 1) * PSTR + (kt & 1) * 32 + k8;
        v8bf ah = as_v8bf(*(const uint4*)&wfsH[koff]);
        v8bf al = as_v8bf(*(const uint4*)&wfsL[koff]);
        int bidx = ((kt << 2) + nt) * 64 + l;
        v8bf bh = as_v8bf(WkpPh[bidx]);
        v8bf bl = as_v8bf(WkpPl[bidx]);
        a0 = __builtin_amdgcn_mfma_f32_16x16x32_bf16(ah, bh, a0, 0, 0, 0);
        a1 = __builtin_amdgcn_mfma_f32_16x16x32_bf16(al, bh, a1, 0, 0, 0);
        a2 = __builtin_amdgcn_mfma_f32_16x16x32_bf16(ah, bl, a2, 0, 0, 0);
    }
    if (khalf == 1) {
        #pragma unroll
        for (int r = 0; r < 4; ++r)
            yP[nt][kg * 4 + r][col] = a0[r] + a1[r] + a2[r];
    }
    __syncthreads();
    if (khalf == 0) {
        #pragma unroll
        for (int r = 0; r < 4; ++r) {
            float yv = lrelu(a0[r] + a1[r] + a2[r] + yP[nt][kg * 4 + r][col]);
            unsigned short hu, lu;
            split1(yv, hu, lu);
            int off = (kg * 4 + r) * YROW + nt * 16 + col;
            yH[off] = hu;
            yL[off] = lu;
        }
    }
    __syncthreads();

    // ---- phase 3: main tail + in-block shortcut, 2 col-tiles/wave ----
    f32x4 acc2[2], accS[2];
    #pragma unroll
    for (int i = 0; i < 2; ++i) {
        acc2[i] = (f32x4){0.f, 0.f, 0.f, 0.f};
        accS[i] = (f32x4){0.f, 0.f, 0.f, 0.f};
    }
    // shortcut GEMM: F[16x128] @ Ws[128x256] (register A, K=128)
    #pragma unroll
    for (int kt = 0; kt < 4; ++kt) {
        float tmp[8] = {fS[kt][0].x, fS[kt][0].y, fS[kt][0].z, fS[kt][0].w,
                        fS[kt][1].x, fS[kt][1].y, fS[kt][1].z, fS[kt][1].w};
        v8bf ah, al;
        split_frag8(tmp, ah, al);
        #pragma unroll
        for (int ii = 0; ii < 2; ++ii) {
            int nt2 = w * 2 + ii;
            int bidx = (((kt << 4) + nt2) << 6) + l;
            v8bf bh = as_v8bf(WsPh[bidx]);
            v8bf bl = as_v8bf(WsPl[bidx]);
            accS[ii] = __builtin_amdgcn_mfma_f32_16x16x32_bf16(ah, bh, accS[ii], 0, 0, 0);
            accS[ii] = __builtin_amdgcn_mfma_f32_16x16x32_bf16(al, bh, accS[ii], 0, 0, 0);
            accS[ii] = __builtin_amdgcn_mfma_f32_16x16x32_bf16(ah, bl, accS[ii], 0, 0, 0);
        }
    }
    // main tail GEMM: y[16x64] @ W2[64x256] (A from LDS, K=64)
    #pragma unroll
    for (int kt = 0; kt < 2; ++kt) {
        int yoff = col * YROW + kt * 32 + k8;
        v8bf ah = as_v8bf(*(const uint4*)&yH[yoff]);
        v8bf al = as_v8bf(*(const uint4*)&yL[yoff]);
        #pragma unroll
        for (int ii = 0; ii < 2; ++ii) {
            int nt2 = w * 2 + ii;
            int bidx = (((kt << 4) + nt2) << 6) + l;
            v8bf bh = as_v8bf(W2Ph[bidx]);
            v8bf bl = as_v8bf(W2Pl[bidx]);
            acc2[ii] = __builtin_amdgcn_mfma_f32_16x16x32_bf16(ah, bh, acc2[ii], 0, 0, 0);
            acc2[ii] = __builtin_amdgcn_mfma_f32_16x16x32_bf16(al, bh, acc2[ii], 0, 0, 0);
            acc2[ii] = __builtin_amdgcn_mfma_f32_16x16x32_bf16(ah, bl, acc2[ii], 0, 0, 0);
        }
    }
    #pragma unroll
    for (int ii = 0; ii < 2; ++ii) {
        int cold = (w * 2 + ii) * 16 + col;
        float sc2 = bnscale[320 + cold], sh2 = bnshift[320 + cold];
        float scS = bnscale[64 + cold],  shS = bnshift[64 + cold];
        #pragma unroll
        for (int r = 0; r < 4; ++r) {
            int n = n0 + kg * 4 + r;
            float mainv = lrelu(acc2[ii][r] * sc2 + sh2);
            float scv   = lrelu(accS[ii][r] * scS + shS);
            out[(size_t)n * COUT + cold] = lrelu(mainv + scv);
        }
    }
}

// ---------------------------------------------------------------------------
extern "C" void kernel_launch(void* const* d_in, const int* in_sizes, int n_in,
                              void* d_out, int out_size, void* d_ws, size_t ws_size,
                              hipStream_t stream)
{
    const float* F   = (const float*)d_in[0];
    const float* pts = (const float*)d_in[1];
    const int*   nid = (const int*)d_in[2];
    const float* W1  = (const float*)d_in[3];
    const float* g1  = (const float*)d_in[4];
    const float* b1  = (const float*)d_in[5];
    const float* m1  = (const float*)d_in[6];
    const float* v1  = (const float*)d_in[7];
    const float* kpp = (const float*)d_in[8];
    const float* Wkp = (const float*)d_in[9];
    const float* W2  = (const float*)d_in[10];
    const float* g2  = (const float*)d_in[11];
    const float* b2  = (const float*)d_in[12];
    const float* m2  = (const float*)d_in[13];
    const float* v2  = (const float*)d_in[14];
    const float* Ws  = (const float*)d_in[15];
    const float* gs  = (const float*)d_in[16];
    const float* bs  = (const float*)d_in[17];
    const float* ms  = (const float*)d_in[18];
    const float* vs  = (const float*)d_in[19];

    const int N = in_sizes[0] / CIN;   // 40000

    unsigned* xp   = (unsigned*)d_ws;                 // [N,64] permuted packed bf16 pair
    uint4* WkpPh   = (uint4*)(xp + (size_t)N * MID);
    uint4* WkpPl   = WkpPh + 7680;
    uint4* W1Ph    = WkpPl + 7680;                    // 1024 each
    uint4* W1Pl    = W1Ph + 1024;
    uint4* WsPh    = W1Pl + 1024;                     // 4096 each
    uint4* WsPl    = WsPh + 4096;
    uint4* W2Ph    = WsPl + 4096;                     // 2048 each
    uint4* W2Pl    = W2Ph + 2048;
    float* bnscale = (float*)(W2Pl + 2048);           // 576
    float* bnshift = bnscale + 576;
    float* out     = (float*)d_out;

    prep<<<61, 256, 0, stream>>>(Wkp, W1, Ws, W2,
                                 g1, b1, m1, v1, gs, bs, ms, vs, g2, b2, m2, v2,
                                 WkpPh, WkpPl, W1Ph, W1Pl, WsPh, WsPl, W2Ph, W2Pl,
                                 bnscale, bnshift);
    k1_mfma<<<N / 64, 256, 0, stream>>>(F, W1Ph, W1Pl, bnscale, bnshift, xp);
    k234_fused<<<N / 16, 512, 0, stream>>>(xp, pts, nid, kpp, F,
                                           WkpPh, WkpPl, W2Ph, W2Pl, WsPh, WsPl,
                                           bnscale, bnshift, out);
}

// Round 9
// 221.196 us; speedup vs baseline: 1.1617x; 1.1617x over previous
//
#include <hip/hip_runtime.h>
#include <math.h>

#define EPSBN 1e-5f

constexpr int CIN  = 128;
constexpr int MID  = 64;
constexpr int COUT = 256;
constexpr int KNB  = 32;
constexpr int PKP  = 15;

constexpr int PSTR = 72;           // wfs p-slot stride (elements); 16B-aligned
constexpr int WROW = PKP * PSTR;   // 1080 elements per point-row
constexpr int YROW = 72;           // y row stride (elements)

typedef __bf16 v8bf  __attribute__((ext_vector_type(8)));
typedef float  f32x4 __attribute__((ext_vector_type(4)));

__device__ __forceinline__ float lrelu(float x) { return x >= 0.0f ? x : 0.1f * x; }

// ---- bf16 split helpers (native cvt; RNE; residual-compensated) ----
__device__ __forceinline__ void split1(float v, unsigned short& h, unsigned short& l) {
    __bf16 hb = (__bf16)v;
    float r = v - (float)hb;
    __bf16 lb = (__bf16)r;
    h = __builtin_bit_cast(unsigned short, hb);
    l = __builtin_bit_cast(unsigned short, lb);
}

__device__ __forceinline__ void split_frag8(const float* s, v8bf& hi, v8bf& lo) {
    #pragma unroll
    for (int j = 0; j < 8; ++j) {
        __bf16 hb = (__bf16)s[j];
        float r = s[j] - (float)hb;
        hi[j] = hb;
        lo[j] = (__bf16)r;
    }
}

__device__ __forceinline__ v8bf as_v8bf(uint4 u) {
    union { uint4 u; v8bf v; } X;
    X.u = u;
    return X.v;
}

// bit-trick split (used by prep only; proven)
__device__ __forceinline__ unsigned bf16_rne(float f) {
    unsigned u = __float_as_uint(f);
    return (u + 0x7fffu + ((u >> 16) & 1u)) >> 16;
}
__device__ __forceinline__ void split_pack8(const float* s, v8bf& hi, v8bf& lo) {
    unsigned h[8], l[8];
    #pragma unroll
    for (int j = 0; j < 8; ++j) {
        float a = s[j];
        unsigned hu = bf16_rne(a);
        float r = a - __uint_as_float(hu << 16);
        h[j] = hu;
        l[j] = bf16_rne(r);
    }
    union { uint4 u; v8bf v; } H, L;
    H.u = make_uint4(h[0] | (h[1] << 16), h[2] | (h[3] << 16),
                     h[4] | (h[5] << 16), h[6] | (h[7] << 16));
    L.u = make_uint4(l[0] | (l[1] << 16), l[2] | (l[3] << 16),
                     l[4] | (l[5] << 16), l[6] | (l[7] << 16));
    hi = H.v;
    lo = L.v;
}

// ---------------------------------------------------------------------------
// prep: pack weights into MFMA B-fragment order (hi/lo bf16), precompute BN.
// B-frag: lane l holds B[k = kt*32+(l>>4)*8+j][col = nt*16+(l&15)], one uint4.
//   Wkp: 30 kt x 4 nt -> 7680 uint4 each; Wc=[W1|Ws]: 4 kt x 20 nt -> 5120;
//   W2: 2 kt x 16 nt -> 2048; bnscale/bnshift[576]: bn1, bns, bn2.
// ---------------------------------------------------------------------------
__global__ __launch_bounds__(256) void prep(
    const float* __restrict__ Wkp, const float* __restrict__ W1,
    const float* __restrict__ Ws,  const float* __restrict__ W2,
    const float* __restrict__ g1, const float* __restrict__ b1,
    const float* __restrict__ m1, const float* __restrict__ v1,
    const float* __restrict__ gs, const float* __restrict__ bs,
    const float* __restrict__ ms, const float* __restrict__ vs,
    const float* __restrict__ g2, const float* __restrict__ b2,
    const float* __restrict__ m2, const float* __restrict__ v2,
    uint4* __restrict__ WkpPh, uint4* __restrict__ WkpPl,
    uint4* __restrict__ WcPh,  uint4* __restrict__ WcPl,
    uint4* __restrict__ W2Ph,  uint4* __restrict__ W2Pl,
    float* __restrict__ bnscale, float* __restrict__ bnshift)
{
    const int b = blockIdx.x, t = threadIdx.x;
    if (b < 30) {                       // Wkp pack
        int gt = b * 256 + t;
        int lane = gt & 63, rest = gt >> 6;
        int nt = rest & 3, kt = rest >> 2;
        int col = nt * 16 + (lane & 15);
        int kbase = kt * 32 + ((lane >> 4) << 3);
        float tmp[8];
        #pragma unroll
        for (int j = 0; j < 8; ++j)
            tmp[j] = Wkp[(size_t)(kbase + j) * MID + col];
        v8bf hi, lo;
        split_pack8(tmp, hi, lo);
        union { v8bf v; uint4 u; } H, L; H.v = hi; L.v = lo;
        WkpPh[gt] = H.u; WkpPl[gt] = L.u;
    } else if (b < 50) {                // Wc = [W1|Ws] pack
        int gt = (b - 30) * 256 + t;
        int lane = gt & 63, rest = gt >> 6;
        int kt = rest / 20, nt = rest % 20;
        int c = nt * 16 + (lane & 15);
        int kbase = kt * 32 + ((lane >> 4) << 3);
        float tmp[8];
        #pragma unroll
        for (int j = 0; j < 8; ++j) {
            int k = kbase + j;
            tmp[j] = (c < 64) ? W1[(size_t)k * MID + c]
                              : Ws[(size_t)k * COUT + (c - 64)];
        }
        v8bf hi, lo;
        split_pack8(tmp, hi, lo);
        union { v8bf v; uint4 u; } H, L; H.v = hi; L.v = lo;
        WcPh[gt] = H.u; WcPl[gt] = L.u;
    } else if (b < 58) {                // W2 pack
        int gt = (b - 50) * 256 + t;
        int lane = gt & 63, rest = gt >> 6;
        int kt = rest >> 4, nt = rest & 15;
        int col = nt * 16 + (lane & 15);
        int kbase = kt * 32 + ((lane >> 4) << 3);
        float tmp[8];
        #pragma unroll
        for (int j = 0; j < 8; ++j)
            tmp[j] = W2[(size_t)(kbase + j) * COUT + col];
        v8bf hi, lo;
        split_pack8(tmp, hi, lo);
        union { v8bf v; uint4 u; } H, L; H.v = hi; L.v = lo;
        W2Ph[gt] = H.u; W2Pl[gt] = L.u;
    } else {                            // BN constants, 576 values
        int v = (b - 58) * 256 + t;
        if (v < 576) {
            float g, bb, mm, vv;
            if (v < 64)       { g = g1[v]; bb = b1[v]; mm = m1[v]; vv = v1[v]; }
            else if (v < 320) { int c = v - 64;  g = gs[c]; bb = bs[c]; mm = ms[c]; vv = vs[c]; }
            else              { int c = v - 320; g = g2[c]; bb = b2[c]; mm = m2[c]; vv = v2[c]; }
            float s = g / sqrtf(vv + EPSBN);
            bnscale[v] = s;
            bnshift[v] = bb - mm * s;
        }
    }
}

// ---------------------------------------------------------------------------
// K1 (MFMA, no LDS): [64 x 128] @ [128 x 160] per block; grid (N/64, 2).
// A-fragments loaded DIRECTLY from F. Cols 0..63 -> xp PERMUTED packed
//   (xp[n*64 + colr*4 + nt] = hi<<16|lo of x[n][nt*16+colr], nt<4) so the
//   k234 gather is one dwordx4 per lane; cols 64..319 -> scbuf f32.
// ---------------------------------------------------------------------------
__global__ __launch_bounds__(256) void k1_mfma(
    const float* __restrict__ F,
    const uint4* __restrict__ WcPh, const uint4* __restrict__ WcPl,
    const float* __restrict__ bnscale, const float* __restrict__ bnshift,
    unsigned* __restrict__ xp, float* __restrict__ scbuf)
{
    const int t = threadIdx.x;
    const int l = t & 63, w = t >> 6;
    const int n0 = blockIdx.x * 64;
    const int ntbase = blockIdx.y * 10;
    const int colr = l & 15, kg = l >> 4;
    const int arow = n0 + w * 16 + colr;
    const int k8 = kg * 8;

    // issue all 8 A loads up-front (4 kt x 2 float4)
    const float* fr = F + (size_t)arow * CIN + k8;
    float4 av[4][2];
    #pragma unroll
    for (int kt = 0; kt < 4; ++kt) {
        av[kt][0] = *(const float4*)(fr + kt * 32);
        av[kt][1] = *(const float4*)(fr + kt * 32 + 4);
    }

    f32x4 acc[10];
    #pragma unroll
    for (int nt = 0; nt < 10; ++nt) acc[nt] = (f32x4){0.f, 0.f, 0.f, 0.f};

    #pragma unroll
    for (int kt = 0; kt < 4; ++kt) {
        float tmp[8] = {av[kt][0].x, av[kt][0].y, av[kt][0].z, av[kt][0].w,
                        av[kt][1].x, av[kt][1].y, av[kt][1].z, av[kt][1].w};
        v8bf ah, al;
        split_frag8(tmp, ah, al);
        #pragma unroll
        for (int nt = 0; nt < 10; ++nt) {
            int bidx = ((kt * 20 + ntbase + nt) << 6) + l;
            v8bf bh = as_v8bf(WcPh[bidx]);
            v8bf bl = as_v8bf(WcPl[bidx]);
            acc[nt] = __builtin_amdgcn_mfma_f32_16x16x32_bf16(ah, bh, acc[nt], 0, 0, 0);
            acc[nt] = __builtin_amdgcn_mfma_f32_16x16x32_bf16(al, bh, acc[nt], 0, 0, 0);
            acc[nt] = __builtin_amdgcn_mfma_f32_16x16x32_bf16(ah, bl, acc[nt], 0, 0, 0);
        }
    }

    const int rq = kg * 4;
    #pragma unroll
    for (int nt = 0; nt < 10; ++nt) {
        int ntg = ntbase + nt;
        int col = ntg * 16 + colr;
        float sc = bnscale[col], sh = bnshift[col];
        #pragma unroll
        for (int r = 0; r < 4; ++r) {
            int row = n0 + w * 16 + rq + r;
            float val = lrelu(acc[nt][r] * sc + sh);
            if (col < 64) {
                unsigned short hu, lu;
                split1(val, hu, lu);
                xp[(size_t)row * MID + colr * 4 + ntg] = ((unsigned)hu << 16) | lu;
            } else {
                scbuf[(size_t)row * COUT + (col - 64)] = val;
            }
        }
    }
}

// ---------------------------------------------------------------------------
// K234 (fused KPConv-MFMA + y-GEMM + tail-GEMM): 512 threads = 8 waves,
// 16 points per block (R7 structure, verified 84us).
// Phase 1: wave w computes wf for points w*2, w*2+1; gather is ONE dwordx4
//   per lane (channel-permuted xp); hi/lo repack via v_perm_b32.
// Phase 2: split-K — wave w handles n-tile (w&3), K-half (w>>2) of 30 kt.
// Phase 3: wave w does 2 of 16 output col-tiles; fused bn2+lrelu+sc+lrelu.
// ---------------------------------------------------------------------------
__global__ __launch_bounds__(512) void k234_fused(
    const unsigned* __restrict__ xp,
    const float* __restrict__ pts,
    const int* __restrict__ nidx,
    const float* __restrict__ kpp,
    const uint4* __restrict__ WkpPh, const uint4* __restrict__ WkpPl,
    const uint4* __restrict__ W2Ph,  const uint4* __restrict__ W2Pl,
    const float* __restrict__ bnscale, const float* __restrict__ bnshift,
    const float* __restrict__ scbuf,
    float* __restrict__ out)
{
    __shared__ unsigned short wfsH[16 * WROW];   // 33.75 KB
    __shared__ unsigned short wfsL[16 * WROW];   // 33.75 KB
    __shared__ float         yP[4][16][17];      // 4.25 KB split-K partials
    __shared__ unsigned short yH[16 * YROW];     // 2.25 KB
    __shared__ unsigned short yL[16 * YROW];     // 2.25 KB

    const int t = threadIdx.x;
    const int l = t & 63, w = t >> 6;            // w in 0..7
    const int col = l & 15, kg = l >> 4;
    const int k8 = kg * 8;
    const int n0 = blockIdx.x * 16;

    // kernel point for this lane's A-row (p = col); p==15 -> h = 0
    float kx = 0.f, ky = 0.f, kz = 0.f;
    if (col < PKP) { kx = kpp[col * 3]; ky = kpp[col * 3 + 1]; kz = kpp[col * 3 + 2]; }

    // ---- phase 1: per-point KPConv via MFMA (2 points per wave) ----
    for (int pt = 0; pt < 2; ++pt) {
        const int pl = w * 2 + pt;
        const int n  = n0 + pl;
        const float cx = pts[(size_t)n * 3];
        const float cy = pts[(size_t)n * 3 + 1];
        const float cz = pts[(size_t)n * 3 + 2];
        const int4 nba = ((const int4*)nidx)[(size_t)n * 8 + kg * 2];
        const int4 nbb = ((const int4*)nidx)[(size_t)n * 8 + kg * 2 + 1];
        int nb[8] = {nba.x, nba.y, nba.z, nba.w, nbb.x, nbb.y, nbb.z, nbb.w};

        // gather packed features: ONE dwordx4 per neighbor (permuted xp);
        // component nt holds channel nt*16+col
        unsigned u[8][4];
        #pragma unroll
        for (int j = 0; j < 8; ++j) {
            uint4 X = ((const uint4*)(xp + (size_t)nb[j] * MID))[col];
            u[j][0] = X.x; u[j][1] = X.y; u[j][2] = X.z; u[j][3] = X.w;
        }

        // influence h for (p=col, k=k8+j) -> A-fragment
        float hv[8];
        #pragma unroll
        for (int j = 0; j < 8; ++j) {
            float ex = (pts[(size_t)nb[j] * 3]     - cx) - kx;
            float ey = (pts[(size_t)nb[j] * 3 + 1] - cy) - ky;
            float ez = (pts[(size_t)nb[j] * 3 + 2] - cz) - kz;
            float dist = sqrtf(ex * ex + ey * ey + ez * ez);
            float h = fmaxf(0.0f, 1.0f - dist * 20.0f);   // 1/KP_EXTENT
            hv[j] = (col < PKP) ? h : 0.0f;
        }
        v8bf ah, al;
        split_frag8(hv, ah, al);

        #pragma unroll
        for (int nt = 0; nt < 4; ++nt) {
            unsigned bhW[4], blW[4];
            #pragma unroll
            for (int i = 0; i < 4; ++i) {
                unsigned u0 = u[2 * i][nt], u1 = u[2 * i + 1][nt];
                bhW[i] = __builtin_amdgcn_perm(u1, u0, 0x07060302u);  // {hi16(u1),hi16(u0)}
                blW[i] = __builtin_amdgcn_perm(u1, u0, 0x05040100u);  // {lo16(u1),lo16(u0)}
            }
            v8bf bh = as_v8bf(make_uint4(bhW[0], bhW[1], bhW[2], bhW[3]));
            v8bf bl = as_v8bf(make_uint4(blW[0], blW[1], blW[2], blW[3]));
            f32x4 acc = {0.f, 0.f, 0.f, 0.f};
            acc = __builtin_amdgcn_mfma_f32_16x16x32_bf16(ah, bh, acc, 0, 0, 0);
            acc = __builtin_amdgcn_mfma_f32_16x16x32_bf16(al, bh, acc, 0, 0, 0);
            acc = __builtin_amdgcn_mfma_f32_16x16x32_bf16(ah, bl, acc, 0, 0, 0);
            // D: row p = kg*4+r, col c = nt*16+col; store pre-split bf16
            #pragma unroll
            for (int r = 0; r < 4; ++r) {
                int p = kg * 4 + r;
                if (p < PKP) {
                    unsigned short hu, lu;
                    split1(acc[r], hu, lu);
                    int off = pl * WROW + p * PSTR + nt * 16 + col;
                    wfsH[off] = hu;
                    wfsL[off] = lu;
                }
            }
        }
    }
    __syncthreads();

    // ---- phase 2: y = wf @ Wkp (K=960) split-K across wave pairs ----
    const int nt = w & 3;        // n-tile
    const int khalf = w >> 2;    // 0: kt 0..14, 1: kt 15..29
    f32x4 a0 = {0.f, 0.f, 0.f, 0.f};
    f32x4 a1 = {0.f, 0.f, 0.f, 0.f};
    f32x4 a2 = {0.f, 0.f, 0.f, 0.f};
    #pragma unroll
    for (int i = 0; i < 15; ++i) {
        int kt = khalf * 15 + i;
        int koff = col * WROW + (kt >> 1) * PSTR + (kt & 1) * 32 + k8;
        v8bf ah = as_v8bf(*(const uint4*)&wfsH[koff]);
        v8bf al = as_v8bf(*(const uint4*)&wfsL[koff]);
        int bidx = ((kt << 2) + nt) * 64 + l;
        v8bf bh = as_v8bf(WkpPh[bidx]);
        v8bf bl = as_v8bf(WkpPl[bidx]);
        a0 = __builtin_amdgcn_mfma_f32_16x16x32_bf16(ah, bh, a0, 0, 0, 0);
        a1 = __builtin_amdgcn_mfma_f32_16x16x32_bf16(al, bh, a1, 0, 0, 0);
        a2 = __builtin_amdgcn_mfma_f32_16x16x32_bf16(ah, bl, a2, 0, 0, 0);
    }
    if (khalf == 1) {
        #pragma unroll
        for (int r = 0; r < 4; ++r)
            yP[nt][kg * 4 + r][col] = a0[r] + a1[r] + a2[r];
    }
    __syncthreads();
    if (khalf == 0) {
        #pragma unroll
        for (int r = 0; r < 4; ++r) {
            float yv = lrelu(a0[r] + a1[r] + a2[r] + yP[nt][kg * 4 + r][col]);
            unsigned short hu, lu;
            split1(yv, hu, lu);
            int off = (kg * 4 + r) * YROW + nt * 16 + col;
            yH[off] = hu;
            yL[off] = lu;
        }
    }
    __syncthreads();

    // ---- phase 3: out = lrelu(lrelu(bn2(y @ W2)) + sc), 2 col-tiles/wave --
    f32x4 acc2[2];
    #pragma unroll
    for (int i = 0; i < 2; ++i) acc2[i] = (f32x4){0.f, 0.f, 0.f, 0.f};
    #pragma unroll
    for (int kt = 0; kt < 2; ++kt) {
        int yoff = col * YROW + kt * 32 + k8;
        v8bf ah = as_v8bf(*(const uint4*)&yH[yoff]);
        v8bf al = as_v8bf(*(const uint4*)&yL[yoff]);
        #pragma unroll
        for (int ii = 0; ii < 2; ++ii) {
            int nt2 = w * 2 + ii;
            int bidx = (((kt << 4) + nt2) << 6) + l;
            v8bf bh = as_v8bf(W2Ph[bidx]);
            v8bf bl = as_v8bf(W2Pl[bidx]);
            acc2[ii] = __builtin_amdgcn_mfma_f32_16x16x32_bf16(ah, bh, acc2[ii], 0, 0, 0);
            acc2[ii] = __builtin_amdgcn_mfma_f32_16x16x32_bf16(al, bh, acc2[ii], 0, 0, 0);
            acc2[ii] = __builtin_amdgcn_mfma_f32_16x16x32_bf16(ah, bl, acc2[ii], 0, 0, 0);
        }
    }
    #pragma unroll
    for (int ii = 0; ii < 2; ++ii) {
        int cold = (w * 2 + ii) * 16 + col;
        float sc = bnscale[320 + cold], sh = bnshift[320 + cold];
        #pragma unroll
        for (int r = 0; r < 4; ++r) {
            int n = n0 + kg * 4 + r;
            float val = lrelu(acc2[ii][r] * sc + sh);
            float scv = scbuf[(size_t)n * COUT + cold];
            out[(size_t)n * COUT + cold] = lrelu(val + scv);
        }
    }
}

// ---------------------------------------------------------------------------
extern "C" void kernel_launch(void* const* d_in, const int* in_sizes, int n_in,
                              void* d_out, int out_size, void* d_ws, size_t ws_size,
                              hipStream_t stream)
{
    const float* F   = (const float*)d_in[0];
    const float* pts = (const float*)d_in[1];
    const int*   nid = (const int*)d_in[2];
    const float* W1  = (const float*)d_in[3];
    const float* g1  = (const float*)d_in[4];
    const float* b1  = (const float*)d_in[5];
    const float* m1  = (const float*)d_in[6];
    const float* v1  = (const float*)d_in[7];
    const float* kpp = (const float*)d_in[8];
    const float* Wkp = (const float*)d_in[9];
    const float* W2  = (const float*)d_in[10];
    const float* g2  = (const float*)d_in[11];
    const float* b2  = (const float*)d_in[12];
    const float* m2  = (const float*)d_in[13];
    const float* v2  = (const float*)d_in[14];
    const float* Ws  = (const float*)d_in[15];
    const float* gs  = (const float*)d_in[16];
    const float* bs  = (const float*)d_in[17];
    const float* ms  = (const float*)d_in[18];
    const float* vs  = (const float*)d_in[19];

    const int N = in_sizes[0] / CIN;   // 40000

    unsigned* xp   = (unsigned*)d_ws;                 // [N,64] permuted packed bf16 pair
    float* scbuf   = (float*)(xp + (size_t)N * MID);  // [N,256] f32
    uint4* WkpPh   = (uint4*)(scbuf + (size_t)N * COUT);
    uint4* WkpPl   = WkpPh + 7680;
    uint4* WcPh    = WkpPl + 7680;
    uint4* WcPl    = WcPh + 5120;
    uint4* W2Ph    = WcPl + 5120;
    uint4* W2Pl    = W2Ph + 2048;
    float* bnscale = (float*)(W2Pl + 2048);           // 576
    float* bnshift = bnscale + 576;
    float* out     = (float*)d_out;

    prep<<<61, 256, 0, stream>>>(Wkp, W1, Ws, W2,
                                 g1, b1, m1, v1, gs, bs, ms, vs, g2, b2, m2, v2,
                                 WkpPh, WkpPl, WcPh, WcPl, W2Ph, W2Pl,
                                 bnscale, bnshift);
    k1_mfma<<<dim3(N / 64, 2), 256, 0, stream>>>(F, WcPh, WcPl, bnscale, bnshift, xp, scbuf);
    k234_fused<<<N / 16, 512, 0, stream>>>(xp, pts, nid, kpp,
                                           WkpPh, WkpPl, W2Ph, W2Pl,
                                           bnscale, bnshift, scbuf, out);
}